// Round 1
// baseline (304.561 us; speedup 1.0000x reference)
//
#include <hip/hip_runtime.h>
#include <cstdint>
#include <cstddef>

#define SEQ 4096
#define DH 2048
#define DOUT 1024

typedef float f32x4 __attribute__((ext_vector_type(4)));
typedef __bf16 bf16x8 __attribute__((ext_vector_type(8)));

// ---- helpers --------------------------------------------------------------

__device__ __forceinline__ unsigned short f2bf(float f) {
  // round-to-nearest-even fp32 -> bf16 (inputs are finite; no NaN handling)
  unsigned int u = __float_as_uint(f);
  unsigned int r = (u + 0x7FFFu + ((u >> 16) & 1u)) >> 16;
  return (unsigned short)r;
}

__device__ __forceinline__ void g2l16(const unsigned short* g, unsigned short* l) {
  // async global -> LDS, 16 bytes per lane. LDS side is wave-uniform base + lane*16.
  __builtin_amdgcn_global_load_lds((__attribute__((address_space(1))) void*)(void*)g,
                                   (__attribute__((address_space(3))) void*)l, 16, 0, 0);
}

// ---- kernel 1: per-row mean / rstd of gate half ---------------------------

__global__ __launch_bounds__(256) void ln_stats(const float* __restrict__ x,
                                                float* __restrict__ mv,
                                                float* __restrict__ rv) {
  int row = blockIdx.x;
  const float4* g4 = (const float4*)(x + (size_t)row * (2 * DH) + DH);
  float4 a = g4[threadIdx.x];
  float4 b = g4[threadIdx.x + 256];
  float s  = a.x + a.y + a.z + a.w + b.x + b.y + b.z + b.w;
  float s2 = a.x * a.x + a.y * a.y + a.z * a.z + a.w * a.w +
             b.x * b.x + b.y * b.y + b.z * b.z + b.w * b.w;
#pragma unroll
  for (int o = 32; o > 0; o >>= 1) {
    s  += __shfl_down(s, o);
    s2 += __shfl_down(s2, o);
  }
  __shared__ float red[8];
  int wave = threadIdx.x >> 6;
  if ((threadIdx.x & 63) == 0) { red[wave] = s; red[wave + 4] = s2; }
  __syncthreads();
  if (threadIdx.x == 0) {
    float S  = red[0] + red[1] + red[2] + red[3];
    float S2 = red[4] + red[5] + red[6] + red[7];
    float mean = S * (1.0f / DH);
    float var  = S2 * (1.0f / DH) - mean * mean;  // ddof=0, matches jnp.var
    mv[row] = mean;
    rv[row] = rsqrtf(var + 1e-5f);
  }
}

// ---- kernel 2: normalize + scale + transpose + cast -> gateT[d][n] bf16 ---

__global__ __launch_bounds__(256) void norm_tr(const float* __restrict__ x,
                                               const float* __restrict__ mv,
                                               const float* __restrict__ rv,
                                               const float* __restrict__ lns,
                                               unsigned short* __restrict__ gateT) {
  __shared__ float tile[64][65];  // +1 pad: conflict-free transposed reads
  int d0 = blockIdx.x * 64;  // d-tile (0..2047)
  int n0 = blockIdx.y * 64;  // n-tile (0..4095)
#pragma unroll
  for (int i = 0; i < 16; i++) {
    int idx = threadIdx.x + i * 256;
    int r = idx >> 6, c = idx & 63;  // r = n offset, c = d offset (coalesced in c)
    float v = x[(size_t)(n0 + r) * (2 * DH) + DH + d0 + c];
    tile[r][c] = (v - mv[n0 + r]) * rv[n0 + r];
  }
  __syncthreads();
#pragma unroll
  for (int i = 0; i < 16; i++) {
    int idx = threadIdx.x + i * 256;
    int dr = idx >> 6, nc = idx & 63;  // coalesced in nc
    float v = tile[nc][dr] * lns[d0 + dr];
    gateT[(size_t)(d0 + dr) * SEQ + n0 + nc] = f2bf(v);
  }
}

// ---- kernel 3: tril-masked cast w fp32 -> bf16 ----------------------------

__global__ __launch_bounds__(256) void cast_w_tril(const float* __restrict__ w,
                                                   unsigned short* __restrict__ wb) {
  size_t e = ((size_t)blockIdx.x * 256 + threadIdx.x) * 8;
  int m = (int)(e >> 12);    // row (4096 = 2^12 cols)
  int k = (int)(e & 4095);   // col
  uint4 o;
  if (k + 7 <= m) {  // fully inside lower triangle
    const float4* s = (const float4*)(w + e);
    float4 a = s[0], b = s[1];
    o.x = (unsigned)f2bf(a.x) | ((unsigned)f2bf(a.y) << 16);
    o.y = (unsigned)f2bf(a.z) | ((unsigned)f2bf(a.w) << 16);
    o.z = (unsigned)f2bf(b.x) | ((unsigned)f2bf(b.y) << 16);
    o.w = (unsigned)f2bf(b.z) | ((unsigned)f2bf(b.w) << 16);
  } else if (k > m) {  // fully above diagonal: no read needed
    o.x = o.y = o.z = o.w = 0u;
  } else {  // straddles the diagonal
    unsigned short t[8];
#pragma unroll
    for (int j = 0; j < 8; j++) t[j] = (k + j <= m) ? f2bf(w[e + j]) : (unsigned short)0;
    o.x = (unsigned)t[0] | ((unsigned)t[1] << 16);
    o.y = (unsigned)t[2] | ((unsigned)t[3] << 16);
    o.z = (unsigned)t[4] | ((unsigned)t[5] << 16);
    o.w = (unsigned)t[6] | ((unsigned)t[7] << 16);
  }
  *(uint4*)(wb + e) = o;
}

// ---- kernel 4: transpose + cast proj_w -> projT[j][d] bf16 ----------------

__global__ __launch_bounds__(256) void proj_tr(const float* __restrict__ pw,
                                               unsigned short* __restrict__ pT) {
  __shared__ float tile[64][65];
  int j0 = blockIdx.x * 64;  // out-col tile (0..1023)
  int d0 = blockIdx.y * 64;  // d tile (0..2047)
#pragma unroll
  for (int i = 0; i < 16; i++) {
    int idx = threadIdx.x + i * 256;
    int r = idx >> 6, c = idx & 63;  // r = d offset, c = j offset
    tile[r][c] = pw[(size_t)(d0 + r) * DOUT + j0 + c];
  }
  __syncthreads();
#pragma unroll
  for (int i = 0; i < 16; i++) {
    int idx = threadIdx.x + i * 256;
    int jr = idx >> 6, dc = idx & 63;
    pT[(size_t)(j0 + jr) * DH + d0 + dc] = f2bf(tile[dc][jr]);
  }
}

// ---- MFMA GEMM: C = A(MxK) * BT(NxK)^T, bf16 in / fp32 acc ----------------
// EPI==1: P[m][n] = bf16( xfull[m][n] * (acc + rbias[m]) )   (gate2 epilogue)
// EPI==2: out[m][n] = acc + cbias[n]
// CAUSAL: skip k-tiles with k0 >= bm0+BM (A pre-masked to tril, so diagonal
//         tiles are already correct).

template <int BM, int BN, bool CAUSAL, int EPI>
__global__ __launch_bounds__(256) void gemm_bt(const unsigned short* __restrict__ A,
                                               const unsigned short* __restrict__ BT,
                                               const float* __restrict__ xfull,
                                               const float* __restrict__ rbias,
                                               unsigned short* __restrict__ Pout,
                                               const float* __restrict__ cbias,
                                               float* __restrict__ out,
                                               int M, int N, int K) {
  constexpr int BK = 32;
  constexpr int WM = BM / 2, WN = BN / 2;       // wave subtile (2x2 wave grid)
  constexpr int AT = WM / 16, BTn = WN / 16;    // 16x16 acc tiles per wave
  constexpr int RA = BM / 64, RB = BN / 64;     // staging rounds (256 thr x 16B = 4KB)
  __shared__ unsigned short sA[BM * BK];
  __shared__ unsigned short sB[BN * BK];

  const int tid = threadIdx.x;
  const int lane = tid & 63, wave = tid >> 6;
  const int quad = lane >> 4, l16 = lane & 15;
  const int wm = wave >> 1, wn = wave & 1;
  const int bm0 = blockIdx.y * BM, bn0 = blockIdx.x * BN;

  // staging pointers: thread t loads 8 bf16 (16B); 4 threads per 32-elem k-row
  const unsigned short* aSrc[RA];
  unsigned short* aDst[RA];
#pragma unroll
  for (int r = 0; r < RA; r++) {
    int row = (r * 256 + tid) >> 2, col = (tid & 3) * 8;
    aSrc[r] = A + (size_t)(bm0 + row) * K + col;
    aDst[r] = &sA[(size_t)(r * 256 + tid) * 8];
  }
  const unsigned short* bSrc[RB];
  unsigned short* bDst[RB];
#pragma unroll
  for (int r = 0; r < RB; r++) {
    int row = (r * 256 + tid) >> 2, col = (tid & 3) * 8;
    bSrc[r] = BT + (size_t)(bn0 + row) * K + col;
    bDst[r] = &sB[(size_t)(r * 256 + tid) * 8];
  }

  f32x4 acc[AT][BTn] = {};

  const int kEnd = CAUSAL ? ((bm0 + BM) < K ? (bm0 + BM) : K) : K;
  for (int k0 = 0; k0 < kEnd; k0 += BK) {
#pragma unroll
    for (int r = 0; r < RA; r++) { g2l16(aSrc[r], aDst[r]); aSrc[r] += BK; }
#pragma unroll
    for (int r = 0; r < RB; r++) { g2l16(bSrc[r], bDst[r]); bSrc[r] += BK; }
    __syncthreads();  // drains vmcnt (global_load_lds) + barrier

    bf16x8 af[AT], bf[BTn];
#pragma unroll
    for (int i = 0; i < AT; i++)
      af[i] = *(const bf16x8*)&sA[(wm * WM + i * 16 + l16) * BK + quad * 8];
#pragma unroll
    for (int j = 0; j < BTn; j++)
      bf[j] = *(const bf16x8*)&sB[(wn * WN + j * 16 + l16) * BK + quad * 8];
#pragma unroll
    for (int i = 0; i < AT; i++)
#pragma unroll
      for (int j = 0; j < BTn; j++)
        acc[i][j] = __builtin_amdgcn_mfma_f32_16x16x32_bf16(af[i], bf[j], acc[i][j], 0, 0, 0);
    __syncthreads();
  }

  // epilogue — C/D layout: col = lane&15, row = quad*4 + reg  (m89-verified)
#pragma unroll
  for (int i = 0; i < AT; i++) {
#pragma unroll
    for (int j = 0; j < BTn; j++) {
      int col = bn0 + wn * WN + j * 16 + l16;
#pragma unroll
      for (int r = 0; r < 4; r++) {
        int row = bm0 + wm * WM + i * 16 + quad * 4 + r;
        float v = acc[i][j][r];
        if (EPI == 1) {
          float g = v + rbias[row];
          float pv = xfull[(size_t)row * (2 * DH) + col] * g;
          Pout[(size_t)row * N + col] = f2bf(pv);
        } else {
          out[(size_t)row * N + col] = v + cbias[col];
        }
      }
    }
  }
}

// ---- launch ---------------------------------------------------------------

extern "C" void kernel_launch(void* const* d_in, const int* in_sizes, int n_in,
                              void* d_out, int out_size, void* d_ws, size_t ws_size,
                              hipStream_t stream) {
  (void)in_sizes; (void)n_in; (void)out_size; (void)ws_size;
  const float* x   = (const float*)d_in[0];
  const float* lns = (const float*)d_in[1];
  const float* w   = (const float*)d_in[2];
  const float* sb  = (const float*)d_in[3];
  const float* pw  = (const float*)d_in[4];
  const float* pb  = (const float*)d_in[5];
  float* out = (float*)d_out;

  char* p = (char*)d_ws;
  unsigned short* gateT = (unsigned short*)p; p += (size_t)DH * SEQ * 2;    // 16 MB
  unsigned short* wb    = (unsigned short*)p; p += (size_t)SEQ * SEQ * 2;   // 32 MB
  unsigned short* projT = (unsigned short*)p; p += (size_t)DOUT * DH * 2;   //  4 MB
  unsigned short* Pbuf  = (unsigned short*)p; p += (size_t)SEQ * DH * 2;    // 16 MB
  float* mv = (float*)p; p += (size_t)SEQ * 4;
  float* rv = (float*)p; p += (size_t)SEQ * 4;

  ln_stats<<<SEQ, 256, 0, stream>>>(x, mv, rv);
  norm_tr<<<dim3(DH / 64, SEQ / 64), 256, 0, stream>>>(x, mv, rv, lns, gateT);
  cast_w_tril<<<(int)(((size_t)SEQ * SEQ / 8) / 256), 256, 0, stream>>>(w, wb);
  proj_tr<<<dim3(DOUT / 64, DH / 64), 256, 0, stream>>>(pw, projT);

  // GEMM1: gate2 = tril(w) @ gate  (M=4096, N=2048, K=4096, causal skip)
  gemm_bt<128, 128, true, 1><<<dim3(DH / 128, SEQ / 128), 256, 0, stream>>>(
      wb, gateT, x, sb, Pbuf, nullptr, nullptr, SEQ, DH, SEQ);
  // GEMM2: out = P @ proj_w + proj_b  (M=4096, N=1024, K=2048)
  gemm_bt<128, 64, false, 2><<<dim3(DOUT / 64, SEQ / 128), 256, 0, stream>>>(
      Pbuf, projT, nullptr, nullptr, nullptr, pb, out, SEQ, DOUT, DH);
}

// Round 2
// 288.715 us; speedup vs baseline: 1.0549x; 1.0549x over previous
//
#include <hip/hip_runtime.h>
#include <cstdint>
#include <cstddef>

#define SEQ 4096
#define DH 2048
#define DOUT 1024

typedef float f32x4 __attribute__((ext_vector_type(4)));
typedef __bf16 bf16x8 __attribute__((ext_vector_type(8)));

// ---- helpers --------------------------------------------------------------

__device__ __forceinline__ unsigned short f2bf(float f) {
  // round-to-nearest-even fp32 -> bf16 (inputs are finite; no NaN handling)
  unsigned int u = __float_as_uint(f);
  unsigned int r = (u + 0x7FFFu + ((u >> 16) & 1u)) >> 16;
  return (unsigned short)r;
}

__device__ __forceinline__ void g2l16(const unsigned short* g, unsigned short* l) {
  // async global -> LDS, 16 bytes per lane. LDS side is wave-uniform base + lane*16.
  __builtin_amdgcn_global_load_lds((__attribute__((address_space(1))) void*)(void*)g,
                                   (__attribute__((address_space(3))) void*)l, 16, 0, 0);
}

// ---- kernel 1: per-row mean / rstd of gate half ---------------------------

__global__ __launch_bounds__(256) void ln_stats(const float* __restrict__ x,
                                                float* __restrict__ mv,
                                                float* __restrict__ rv) {
  int row = blockIdx.x;
  const float4* g4 = (const float4*)(x + (size_t)row * (2 * DH) + DH);
  float4 a = g4[threadIdx.x];
  float4 b = g4[threadIdx.x + 256];
  float s  = a.x + a.y + a.z + a.w + b.x + b.y + b.z + b.w;
  float s2 = a.x * a.x + a.y * a.y + a.z * a.z + a.w * a.w +
             b.x * b.x + b.y * b.y + b.z * b.z + b.w * b.w;
#pragma unroll
  for (int o = 32; o > 0; o >>= 1) {
    s  += __shfl_down(s, o);
    s2 += __shfl_down(s2, o);
  }
  __shared__ float red[8];
  int wave = threadIdx.x >> 6;
  if ((threadIdx.x & 63) == 0) { red[wave] = s; red[wave + 4] = s2; }
  __syncthreads();
  if (threadIdx.x == 0) {
    float S  = red[0] + red[1] + red[2] + red[3];
    float S2 = red[4] + red[5] + red[6] + red[7];
    float mean = S * (1.0f / DH);
    float var  = S2 * (1.0f / DH) - mean * mean;  // ddof=0, matches jnp.var
    mv[row] = mean;
    rv[row] = rsqrtf(var + 1e-5f);
  }
}

// ---- kernel 2: normalize + scale + transpose + cast -> gateT[d][n] bf16 ---

__global__ __launch_bounds__(256) void norm_tr(const float* __restrict__ x,
                                               const float* __restrict__ mv,
                                               const float* __restrict__ rv,
                                               const float* __restrict__ lns,
                                               unsigned short* __restrict__ gateT) {
  __shared__ float tile[64][65];  // +1 pad: conflict-free transposed reads
  int d0 = blockIdx.x * 64;  // d-tile (0..2047)
  int n0 = blockIdx.y * 64;  // n-tile (0..4095)
#pragma unroll
  for (int i = 0; i < 16; i++) {
    int idx = threadIdx.x + i * 256;
    int r = idx >> 6, c = idx & 63;  // r = n offset, c = d offset (coalesced in c)
    float v = x[(size_t)(n0 + r) * (2 * DH) + DH + d0 + c];
    tile[r][c] = (v - mv[n0 + r]) * rv[n0 + r];
  }
  __syncthreads();
#pragma unroll
  for (int i = 0; i < 16; i++) {
    int idx = threadIdx.x + i * 256;
    int dr = idx >> 6, nc = idx & 63;  // coalesced in nc
    float v = tile[nc][dr] * lns[d0 + dr];
    gateT[(size_t)(d0 + dr) * SEQ + n0 + nc] = f2bf(v);
  }
}

// ---- kernel 3: tril-masked cast w fp32 -> bf16 ----------------------------

__global__ __launch_bounds__(256) void cast_w_tril(const float* __restrict__ w,
                                                   unsigned short* __restrict__ wb) {
  size_t e = ((size_t)blockIdx.x * 256 + threadIdx.x) * 8;
  int m = (int)(e >> 12);    // row (4096 = 2^12 cols)
  int k = (int)(e & 4095);   // col
  uint4 o;
  if (k + 7 <= m) {  // fully inside lower triangle
    const float4* s = (const float4*)(w + e);
    float4 a = s[0], b = s[1];
    o.x = (unsigned)f2bf(a.x) | ((unsigned)f2bf(a.y) << 16);
    o.y = (unsigned)f2bf(a.z) | ((unsigned)f2bf(a.w) << 16);
    o.z = (unsigned)f2bf(b.x) | ((unsigned)f2bf(b.y) << 16);
    o.w = (unsigned)f2bf(b.z) | ((unsigned)f2bf(b.w) << 16);
  } else if (k > m) {  // fully above diagonal: no read needed
    o.x = o.y = o.z = o.w = 0u;
  } else {  // straddles the diagonal
    unsigned short t[8];
#pragma unroll
    for (int j = 0; j < 8; j++) t[j] = (k + j <= m) ? f2bf(w[e + j]) : (unsigned short)0;
    o.x = (unsigned)t[0] | ((unsigned)t[1] << 16);
    o.y = (unsigned)t[2] | ((unsigned)t[3] << 16);
    o.z = (unsigned)t[4] | ((unsigned)t[5] << 16);
    o.w = (unsigned)t[6] | ((unsigned)t[7] << 16);
  }
  *(uint4*)(wb + e) = o;
}

// ---- kernel 4: transpose + cast proj_w -> projT[j][d] bf16 ----------------

__global__ __launch_bounds__(256) void proj_tr(const float* __restrict__ pw,
                                               unsigned short* __restrict__ pT) {
  __shared__ float tile[64][65];
  int j0 = blockIdx.x * 64;  // out-col tile (0..1023)
  int d0 = blockIdx.y * 64;  // d tile (0..2047)
#pragma unroll
  for (int i = 0; i < 16; i++) {
    int idx = threadIdx.x + i * 256;
    int r = idx >> 6, c = idx & 63;  // r = d offset, c = j offset
    tile[r][c] = pw[(size_t)(d0 + r) * DOUT + j0 + c];
  }
  __syncthreads();
#pragma unroll
  for (int i = 0; i < 16; i++) {
    int idx = threadIdx.x + i * 256;
    int jr = idx >> 6, dc = idx & 63;
    pT[(size_t)(j0 + jr) * DH + d0 + dc] = f2bf(tile[dc][jr]);
  }
}

// ---- MFMA GEMM: C = A(MxK) * BT(NxK)^T, bf16 in / fp32 acc ----------------
// EPI==1: P[m][n] = bf16( xfull[m][n] * (acc + rbias[m]) )   (gate2 epilogue)
// EPI==2: out[m][n] = acc + cbias[n]
// CAUSAL: skip k-tiles with k0 >= bm0+BM (A pre-masked to tril, so diagonal
//         tiles are already correct). BALANCE remaps row-blocks so that under
//         round-robin dispatch each CU's row-block set {g,15-g,16+g,31-g} has
//         constant total k-work (sum = 62+4 rows-worth per CU).
// LDS layout is XOR-chunk-swizzled: data chunk c of row R lives at physical
// chunk c^(R&3). Applied on the staging SOURCE side (global_load_lds's LDS
// destination is lane-fixed), and compensated in the fragment reads. Breaks
// the 8-way bank conflict of the 64B-row-stride layout.

template <int BM, int BN, bool CAUSAL, bool BALANCE, int EPI>
__global__ __launch_bounds__(256) void gemm_bt(const unsigned short* __restrict__ A,
                                               const unsigned short* __restrict__ BT,
                                               const float* __restrict__ xfull,
                                               const float* __restrict__ rbias,
                                               unsigned short* __restrict__ Pout,
                                               const float* __restrict__ cbias,
                                               float* __restrict__ out,
                                               int M, int N, int K) {
  constexpr int BK = 32;
  constexpr int WM = BM / 2, WN = BN / 2;       // wave subtile (2x2 wave grid)
  constexpr int AT = WM / 16, BTn = WN / 16;    // 16x16 acc tiles per wave
  constexpr int RA = BM / 64, RB = BN / 64;     // staging rounds (256 thr x 16B = 4KB)
  __shared__ unsigned short sA[BM * BK];
  __shared__ unsigned short sB[BN * BK];

  const int tid = threadIdx.x;
  const int lane = tid & 63, wave = tid >> 6;
  const int quad = lane >> 4, l16 = lane & 15;
  const int wm = wave >> 1, wn = wave & 1;

  int by = blockIdx.y;
  if (BALANCE) {
    int j = by >> 3, g = by & 7;
    by = (j == 0) ? g : (j == 1) ? 15 - g : (j == 2) ? 16 + g : 31 - g;
  }
  const int bm0 = by * BM, bn0 = blockIdx.x * BN;

  // staging: thread t -> row t>>2, data-chunk t&3, PHYSICAL chunk (t&3)^(row&3)
  // so the global source chunk for physical slot t is (t&3)^((t>>2)&3).
  const unsigned short* aSrc[RA];
  unsigned short* aDst[RA];
#pragma unroll
  for (int r = 0; r < RA; r++) {
    int row = (r * 256 + tid) >> 2;
    int col = (((r * 256 + tid) & 3) ^ (row & 3)) * 8;
    aSrc[r] = A + (size_t)(bm0 + row) * K + col;
    aDst[r] = &sA[(size_t)(r * 256 + tid) * 8];
  }
  const unsigned short* bSrc[RB];
  unsigned short* bDst[RB];
#pragma unroll
  for (int r = 0; r < RB; r++) {
    int row = (r * 256 + tid) >> 2;
    int col = (((r * 256 + tid) & 3) ^ (row & 3)) * 8;
    bSrc[r] = BT + (size_t)(bn0 + row) * K + col;
    bDst[r] = &sB[(size_t)(r * 256 + tid) * 8];
  }

  f32x4 acc[AT][BTn] = {};

  const int kEnd = CAUSAL ? ((bm0 + BM) < K ? (bm0 + BM) : K) : K;
  for (int k0 = 0; k0 < kEnd; k0 += BK) {
#pragma unroll
    for (int r = 0; r < RA; r++) { g2l16(aSrc[r], aDst[r]); aSrc[r] += BK; }
#pragma unroll
    for (int r = 0; r < RB; r++) { g2l16(bSrc[r], bDst[r]); bSrc[r] += BK; }
    __syncthreads();  // drains vmcnt (global_load_lds) + barrier

    bf16x8 af[AT], bf[BTn];
#pragma unroll
    for (int i = 0; i < AT; i++) {
      int R = wm * WM + i * 16 + l16;
      af[i] = *(const bf16x8*)&sA[R * BK + ((quad ^ (R & 3)) * 8)];
    }
#pragma unroll
    for (int j = 0; j < BTn; j++) {
      int R = wn * WN + j * 16 + l16;
      bf[j] = *(const bf16x8*)&sB[R * BK + ((quad ^ (R & 3)) * 8)];
    }
#pragma unroll
    for (int i = 0; i < AT; i++)
#pragma unroll
      for (int j = 0; j < BTn; j++)
        acc[i][j] = __builtin_amdgcn_mfma_f32_16x16x32_bf16(af[i], bf[j], acc[i][j], 0, 0, 0);
    __syncthreads();
  }

  // epilogue — C/D layout: col = lane&15, row = quad*4 + reg  (m89-verified)
#pragma unroll
  for (int i = 0; i < AT; i++) {
#pragma unroll
    for (int j = 0; j < BTn; j++) {
      int col = bn0 + wn * WN + j * 16 + l16;
#pragma unroll
      for (int r = 0; r < 4; r++) {
        int row = bm0 + wm * WM + i * 16 + quad * 4 + r;
        float v = acc[i][j][r];
        if (EPI == 1) {
          float g = v + rbias[row];
          float pv = xfull[(size_t)row * (2 * DH) + col] * g;
          Pout[(size_t)row * N + col] = f2bf(pv);
        } else {
          out[(size_t)row * N + col] = v + cbias[col];
        }
      }
    }
  }
}

// ---- launch ---------------------------------------------------------------

extern "C" void kernel_launch(void* const* d_in, const int* in_sizes, int n_in,
                              void* d_out, int out_size, void* d_ws, size_t ws_size,
                              hipStream_t stream) {
  (void)in_sizes; (void)n_in; (void)out_size; (void)ws_size;
  const float* x   = (const float*)d_in[0];
  const float* lns = (const float*)d_in[1];
  const float* w   = (const float*)d_in[2];
  const float* sb  = (const float*)d_in[3];
  const float* pw  = (const float*)d_in[4];
  const float* pb  = (const float*)d_in[5];
  float* out = (float*)d_out;

  char* p = (char*)d_ws;
  unsigned short* gateT = (unsigned short*)p; p += (size_t)DH * SEQ * 2;    // 16 MB
  unsigned short* wb    = (unsigned short*)p; p += (size_t)SEQ * SEQ * 2;   // 32 MB
  unsigned short* projT = (unsigned short*)p; p += (size_t)DOUT * DH * 2;   //  4 MB
  unsigned short* Pbuf  = (unsigned short*)p; p += (size_t)SEQ * DH * 2;    // 16 MB
  float* mv = (float*)p; p += (size_t)SEQ * 4;
  float* rv = (float*)p; p += (size_t)SEQ * 4;

  ln_stats<<<SEQ, 256, 0, stream>>>(x, mv, rv);
  norm_tr<<<dim3(DH / 64, SEQ / 64), 256, 0, stream>>>(x, mv, rv, lns, gateT);
  cast_w_tril<<<(int)(((size_t)SEQ * SEQ / 8) / 256), 256, 0, stream>>>(w, wb);
  proj_tr<<<dim3(DOUT / 64, DH / 64), 256, 0, stream>>>(pw, projT);

  // GEMM1: gate2 = tril(w) @ gate  (M=4096, N=2048, K=4096, causal skip)
  // BM=128, BN=64 -> grid (32,32)=1024 blocks = 4/CU, causal-balanced rows.
  gemm_bt<128, 64, true, true, 1><<<dim3(DH / 64, SEQ / 128), 256, 0, stream>>>(
      wb, gateT, x, sb, Pbuf, nullptr, nullptr, SEQ, DH, SEQ);
  // GEMM2: out = P @ proj_w + proj_b  (M=4096, N=1024, K=2048)
  gemm_bt<128, 64, false, false, 2><<<dim3(DOUT / 64, SEQ / 128), 256, 0, stream>>>(
      Pbuf, projT, nullptr, nullptr, nullptr, pb, out, SEQ, DOUT, DH);
}

// Round 3
// 255.349 us; speedup vs baseline: 1.1927x; 1.1307x over previous
//
#include <hip/hip_runtime.h>
#include <cstdint>
#include <cstddef>

#define SEQ 4096
#define DH 2048
#define DOUT 1024

typedef float f32x4 __attribute__((ext_vector_type(4)));
typedef __bf16 bf16x8 __attribute__((ext_vector_type(8)));

// ---- helpers --------------------------------------------------------------

__device__ __forceinline__ unsigned short f2bf(float f) {
  // round-to-nearest-even fp32 -> bf16 (inputs are finite; no NaN handling)
  unsigned int u = __float_as_uint(f);
  unsigned int r = (u + 0x7FFFu + ((u >> 16) & 1u)) >> 16;
  return (unsigned short)r;
}

__device__ __forceinline__ void g2l16(const unsigned short* g, unsigned short* l) {
  // async global -> LDS, 16 bytes per lane. LDS side is wave-uniform base + lane*16.
  __builtin_amdgcn_global_load_lds((__attribute__((address_space(1))) void*)(void*)g,
                                   (__attribute__((address_space(3))) void*)l, 16, 0, 0);
}

// ---- kernel 1: per-row mean / rstd of gate half ---------------------------

__global__ __launch_bounds__(256) void ln_stats(const float* __restrict__ x,
                                                float* __restrict__ mv,
                                                float* __restrict__ rv) {
  int row = blockIdx.x;
  const float4* g4 = (const float4*)(x + (size_t)row * (2 * DH) + DH);
  float4 a = g4[threadIdx.x];
  float4 b = g4[threadIdx.x + 256];
  float s  = a.x + a.y + a.z + a.w + b.x + b.y + b.z + b.w;
  float s2 = a.x * a.x + a.y * a.y + a.z * a.z + a.w * a.w +
             b.x * b.x + b.y * b.y + b.z * b.z + b.w * b.w;
#pragma unroll
  for (int o = 32; o > 0; o >>= 1) {
    s  += __shfl_down(s, o);
    s2 += __shfl_down(s2, o);
  }
  __shared__ float red[8];
  int wave = threadIdx.x >> 6;
  if ((threadIdx.x & 63) == 0) { red[wave] = s; red[wave + 4] = s2; }
  __syncthreads();
  if (threadIdx.x == 0) {
    float S  = red[0] + red[1] + red[2] + red[3];
    float S2 = red[4] + red[5] + red[6] + red[7];
    float mean = S * (1.0f / DH);
    float var  = S2 * (1.0f / DH) - mean * mean;  // ddof=0, matches jnp.var
    mv[row] = mean;
    rv[row] = rsqrtf(var + 1e-5f);
  }
}

// ---- kernel 2: normalize + scale + transpose + cast -> gateT[d][n] bf16 ---

__global__ __launch_bounds__(256) void norm_tr(const float* __restrict__ x,
                                               const float* __restrict__ mv,
                                               const float* __restrict__ rv,
                                               const float* __restrict__ lns,
                                               unsigned short* __restrict__ gateT) {
  __shared__ float tile[64][65];  // +1 pad: conflict-free transposed reads
  int d0 = blockIdx.x * 64;  // d-tile (0..2047)
  int n0 = blockIdx.y * 64;  // n-tile (0..4095)
#pragma unroll
  for (int i = 0; i < 16; i++) {
    int idx = threadIdx.x + i * 256;
    int r = idx >> 6, c = idx & 63;  // r = n offset, c = d offset (coalesced in c)
    float v = x[(size_t)(n0 + r) * (2 * DH) + DH + d0 + c];
    tile[r][c] = (v - mv[n0 + r]) * rv[n0 + r];
  }
  __syncthreads();
#pragma unroll
  for (int i = 0; i < 16; i++) {
    int idx = threadIdx.x + i * 256;
    int dr = idx >> 6, nc = idx & 63;  // coalesced in nc
    float v = tile[nc][dr] * lns[d0 + dr];
    gateT[(size_t)(d0 + dr) * SEQ + n0 + nc] = f2bf(v);
  }
}

// ---- kernel 3: tril-masked cast w fp32 -> bf16 ----------------------------

__global__ __launch_bounds__(256) void cast_w_tril(const float* __restrict__ w,
                                                   unsigned short* __restrict__ wb) {
  size_t e = ((size_t)blockIdx.x * 256 + threadIdx.x) * 8;
  int m = (int)(e >> 12);    // row (4096 = 2^12 cols)
  int k = (int)(e & 4095);   // col
  uint4 o;
  if (k + 7 <= m) {  // fully inside lower triangle
    const float4* s = (const float4*)(w + e);
    float4 a = s[0], b = s[1];
    o.x = (unsigned)f2bf(a.x) | ((unsigned)f2bf(a.y) << 16);
    o.y = (unsigned)f2bf(a.z) | ((unsigned)f2bf(a.w) << 16);
    o.z = (unsigned)f2bf(b.x) | ((unsigned)f2bf(b.y) << 16);
    o.w = (unsigned)f2bf(b.z) | ((unsigned)f2bf(b.w) << 16);
  } else if (k > m) {  // fully above diagonal: no read needed
    o.x = o.y = o.z = o.w = 0u;
  } else {  // straddles the diagonal
    unsigned short t[8];
#pragma unroll
    for (int j = 0; j < 8; j++) t[j] = (k + j <= m) ? f2bf(w[e + j]) : (unsigned short)0;
    o.x = (unsigned)t[0] | ((unsigned)t[1] << 16);
    o.y = (unsigned)t[2] | ((unsigned)t[3] << 16);
    o.z = (unsigned)t[4] | ((unsigned)t[5] << 16);
    o.w = (unsigned)t[6] | ((unsigned)t[7] << 16);
  }
  *(uint4*)(wb + e) = o;
}

// ---- kernel 4: transpose + cast proj_w -> projT[j][d] bf16 ----------------

__global__ __launch_bounds__(256) void proj_tr(const float* __restrict__ pw,
                                               unsigned short* __restrict__ pT) {
  __shared__ float tile[64][65];
  int j0 = blockIdx.x * 64;  // out-col tile (0..1023)
  int d0 = blockIdx.y * 64;  // d tile (0..2047)
#pragma unroll
  for (int i = 0; i < 16; i++) {
    int idx = threadIdx.x + i * 256;
    int r = idx >> 6, c = idx & 63;  // r = d offset, c = j offset
    tile[r][c] = pw[(size_t)(d0 + r) * DOUT + j0 + c];
  }
  __syncthreads();
#pragma unroll
  for (int i = 0; i < 16; i++) {
    int idx = threadIdx.x + i * 256;
    int jr = idx >> 6, dc = idx & 63;
    pT[(size_t)(j0 + jr) * DH + d0 + dc] = f2bf(tile[dc][jr]);
  }
}

// ---- MFMA GEMM, 64x64 tile, BK=64: C = A(MxK) * BT(NxK)^T ----------------
// bf16 in / fp32 acc. 256 threads = 4 waves in a 2x2 grid, each wave owns a
// 32x32 subtile (2x2 16x16 acc tiles), 8 MFMA per wave per BK=64 iter.
//
// PAIR (GEMM1 causal): block p processes row-blocks {p, 63-p} sequentially,
//   each up to its diagonal (kEnd = bm0+64). Every block does exactly 65
//   k-iters -> perfectly uniform grid, no occupancy tail. A is pre-masked
//   to tril so diagonal tiles are correct.
// EPI==1: P[m][n] = bf16( xfull[m][n] * (acc + rbias[m]) )
// EPI==2: out[m][n] = acc + cbias[n]
//
// LDS: 128 B rows (BK=64 bf16). Row stride = exactly 32 banks, so bank-group
// of a 16 B chunk = its chunk index. XOR-8 swizzle: data chunk c of row R is
// stored at physical chunk c^(R&7). Fragment reads then hit each of the 8
// bank-groups with exactly 2 lanes per 16-lane phase = conflict-free.

template <bool PAIR, int EPI>
__global__ __launch_bounds__(256) void gemm64(const unsigned short* __restrict__ A,
                                              const unsigned short* __restrict__ BT,
                                              const float* __restrict__ xfull,
                                              const float* __restrict__ rbias,
                                              unsigned short* __restrict__ Pout,
                                              const float* __restrict__ cbias,
                                              float* __restrict__ out,
                                              int N, int K) {
  constexpr int BM = 64, BN = 64, BK = 64;
  __shared__ unsigned short sA[BM * BK];
  __shared__ unsigned short sB[BN * BK];

  const int tid = threadIdx.x;
  const int lane = tid & 63, wave = tid >> 6;
  const int quad = lane >> 4, l16 = lane & 15;
  const int wm = wave >> 1, wn = wave & 1;
  const int bn0 = blockIdx.x * BN;

  // B staging source offsets (row/chunk swizzled), fixed across tiles
  int sRow[2], sCol[2];
#pragma unroll
  for (int r = 0; r < 2; r++) {
    int idx = r * 256 + tid;
    int row = idx >> 3;
    sRow[r] = row;
    sCol[r] = ((idx & 7) ^ (row & 7)) * 8;
  }

  const int nTiles = PAIR ? 2 : 1;
  for (int t = 0; t < nTiles; t++) {
    const int by = PAIR ? (t == 0 ? (int)blockIdx.y : (2 * (int)gridDim.y - 1 - (int)blockIdx.y))
                        : (int)blockIdx.y;
    const int bm0 = by * BM;
    const int kEnd = PAIR ? (bm0 + BM) : K;

    const unsigned short* aSrc[2];
    const unsigned short* bSrc[2];
    unsigned short* aDst[2];
    unsigned short* bDst[2];
#pragma unroll
    for (int r = 0; r < 2; r++) {
      aSrc[r] = A + (size_t)(bm0 + sRow[r]) * K + sCol[r];
      bSrc[r] = BT + (size_t)(bn0 + sRow[r]) * K + sCol[r];
      aDst[r] = &sA[(size_t)(r * 256 + tid) * 8];
      bDst[r] = &sB[(size_t)(r * 256 + tid) * 8];
    }

    f32x4 acc[2][2] = {};

    for (int k0 = 0; k0 < kEnd; k0 += BK) {
#pragma unroll
      for (int r = 0; r < 2; r++) { g2l16(aSrc[r], aDst[r]); aSrc[r] += BK; }
#pragma unroll
      for (int r = 0; r < 2; r++) { g2l16(bSrc[r], bDst[r]); bSrc[r] += BK; }
      __syncthreads();  // drains vmcnt (global_load_lds) + barrier

      bf16x8 af[2][2], bf[2][2];
#pragma unroll
      for (int h = 0; h < 2; h++) {
#pragma unroll
        for (int i = 0; i < 2; i++) {
          int R = wm * 32 + i * 16 + l16;
          af[h][i] = *(const bf16x8*)&sA[R * BK + (((h * 4 + quad) ^ (R & 7)) * 8)];
        }
#pragma unroll
        for (int j = 0; j < 2; j++) {
          int R = wn * 32 + j * 16 + l16;
          bf[h][j] = *(const bf16x8*)&sB[R * BK + (((h * 4 + quad) ^ (R & 7)) * 8)];
        }
      }
#pragma unroll
      for (int h = 0; h < 2; h++)
#pragma unroll
        for (int i = 0; i < 2; i++)
#pragma unroll
          for (int j = 0; j < 2; j++)
            acc[i][j] = __builtin_amdgcn_mfma_f32_16x16x32_bf16(af[h][i], bf[h][j], acc[i][j], 0, 0, 0);
      __syncthreads();
    }

    // epilogue — C/D layout: col = lane&15, row = quad*4 + reg (m89-verified)
#pragma unroll
    for (int i = 0; i < 2; i++) {
#pragma unroll
      for (int j = 0; j < 2; j++) {
        int col = bn0 + wn * 32 + j * 16 + l16;
#pragma unroll
        for (int r = 0; r < 4; r++) {
          int row = bm0 + wm * 32 + i * 16 + quad * 4 + r;
          float v = acc[i][j][r];
          if (EPI == 1) {
            float g = v + rbias[row];
            float pv = xfull[(size_t)row * (2 * DH) + col] * g;
            Pout[(size_t)row * N + col] = f2bf(pv);
          } else {
            out[(size_t)row * N + col] = v + cbias[col];
          }
        }
      }
    }
    if (PAIR && t == 0) __syncthreads();  // LDS reuse hazard between tiles
  }
}

// ---- launch ---------------------------------------------------------------

extern "C" void kernel_launch(void* const* d_in, const int* in_sizes, int n_in,
                              void* d_out, int out_size, void* d_ws, size_t ws_size,
                              hipStream_t stream) {
  (void)in_sizes; (void)n_in; (void)out_size; (void)ws_size;
  const float* x   = (const float*)d_in[0];
  const float* lns = (const float*)d_in[1];
  const float* w   = (const float*)d_in[2];
  const float* sb  = (const float*)d_in[3];
  const float* pw  = (const float*)d_in[4];
  const float* pb  = (const float*)d_in[5];
  float* out = (float*)d_out;

  char* p = (char*)d_ws;
  unsigned short* gateT = (unsigned short*)p; p += (size_t)DH * SEQ * 2;    // 16 MB
  unsigned short* wb    = (unsigned short*)p; p += (size_t)SEQ * SEQ * 2;   // 32 MB
  unsigned short* projT = (unsigned short*)p; p += (size_t)DOUT * DH * 2;   //  4 MB
  unsigned short* Pbuf  = (unsigned short*)p; p += (size_t)SEQ * DH * 2;    // 16 MB
  float* mv = (float*)p; p += (size_t)SEQ * 4;
  float* rv = (float*)p; p += (size_t)SEQ * 4;

  ln_stats<<<SEQ, 256, 0, stream>>>(x, mv, rv);
  norm_tr<<<dim3(DH / 64, SEQ / 64), 256, 0, stream>>>(x, mv, rv, lns, gateT);
  cast_w_tril<<<(int)(((size_t)SEQ * SEQ / 8) / 256), 256, 0, stream>>>(w, wb);
  proj_tr<<<dim3(DOUT / 64, DH / 64), 256, 0, stream>>>(pw, projT);

  // GEMM1: gate2 = tril(w) @ gate  (M=4096, N=2048, K=4096)
  // Triangular pairing: block p does row-blocks {p, 63-p} -> 65 iters each,
  // grid (32,32)=1024 uniform blocks = 4/CU.
  gemm64<true, 1><<<dim3(DH / 64, SEQ / 128), 256, 0, stream>>>(
      wb, gateT, x, sb, Pbuf, nullptr, nullptr, DH, SEQ);
  // GEMM2: out = P @ proj_w + proj_b  (M=4096, N=1024, K=2048)
  // grid (16,64)=1024 uniform blocks, 32 iters each.
  gemm64<false, 2><<<dim3(DOUT / 64, SEQ / 64), 256, 0, stream>>>(
      Pbuf, projT, nullptr, nullptr, nullptr, pb, out, DOUT, DH);
}